// Round 3
// baseline (2427.878 us; speedup 1.0000x reference)
//
#include <hip/hip_runtime.h>
#include <math.h>

#define N_NODES 100000
#define N_EDGES 800000
#define NBLK 391  // ceil(N_NODES/256)

// ----------------------------------------------------------- CSR construction
__global__ void k_count(const int* __restrict__ col, int* __restrict__ cnt) {
    int e = blockIdx.x * 256 + threadIdx.x;
    if (e < N_EDGES) {
        unsigned c = (unsigned)col[e];
        if (c < N_NODES) atomicAdd(&cnt[c], 1);
    }
}

__global__ void k_blocksum(const int* __restrict__ cnt, int* __restrict__ bsum) {
    __shared__ int sc[256];
    int t = threadIdx.x, i = blockIdx.x * 256 + t;
    sc[t] = (i < N_NODES) ? cnt[i] : 0;
    __syncthreads();
    for (int o = 128; o; o >>= 1) {
        if (t < o) sc[t] += sc[t + o];
        __syncthreads();
    }
    if (t == 0) bsum[blockIdx.x] = sc[0];
}

__global__ void k_scanblocks(const int* __restrict__ bsum, int* __restrict__ bexcl) {
    if (threadIdx.x == 0) {
        int run = 0;
        for (int b = 0; b < NBLK; b++) { bexcl[b] = run; run += bsum[b]; }
    }
}

__global__ void k_offsets(const int* __restrict__ cnt, const int* __restrict__ bexcl,
                          int* __restrict__ off, int* __restrict__ pos) {
    __shared__ int sc[256];
    int t = threadIdx.x, i = blockIdx.x * 256 + t;
    int v = (i < N_NODES) ? cnt[i] : 0;
    sc[t] = v;
    __syncthreads();
    for (int o = 1; o < 256; o <<= 1) {
        int tv = (t >= o) ? sc[t - o] : 0;
        __syncthreads();
        sc[t] += tv;
        __syncthreads();
    }
    if (i < N_NODES) {
        int s = bexcl[blockIdx.x] + (sc[t] - v);
        off[i] = s;
        pos[i] = s;
    }
}

__global__ void k_dinv(const int* __restrict__ cnt, float* __restrict__ dinv) {
    int i = blockIdx.x * 256 + threadIdx.x;
    if (i < N_NODES) dinv[i] = rsqrtf((float)(cnt[i] + 1)); // +1 self-loop
}

__global__ void k_build(const int* __restrict__ row, const int* __restrict__ col,
                        int* __restrict__ pos, int* __restrict__ srcE, int* __restrict__ eidE) {
    int e = blockIdx.x * 256 + threadIdx.x;
    if (e < N_EDGES) {
        unsigned r = (unsigned)row[e], c = (unsigned)col[e];
        if (r < N_NODES && c < N_NODES) {
            int slot = atomicAdd(&pos[c], 1);
            srcE[slot] = (int)r;
            eidE[slot] = e;
        }
    }
}

// ------------------------------------------- fused gather + GEMM + bias + GELU
// mode 0: X=x, gather edge_attr rows (EAraw), emit unscaled edge-agg to EaOut
// mode 1: X=h1, read pre-aggregated EaIn
// out[c] = gelu( [dinv*agg + dinv^2*X[c] | dinv*Ea[c]] @ [Wn;We] + bias )
__global__ __launch_bounds__(256) void k_layer(
    const float* __restrict__ X, const float* __restrict__ EAraw,
    const float* __restrict__ EaIn, float* __restrict__ EaOut,
    const int* __restrict__ off, const int* __restrict__ cnt,
    const int* __restrict__ srcE, const int* __restrict__ eidE,
    const float* __restrict__ dinv,
    const float* __restrict__ Wn, const float* __restrict__ We,
    const float* __restrict__ bias, float* __restrict__ out, int mode)
{
    __shared__ float act[4][4][192];
    int w = threadIdx.x >> 6, l = threadIdx.x & 63;
    int row0 = blockIdx.x * 16 + w * 4;

    for (int r = 0; r < 4; r++) {
        int c = row0 + r;
        int beg = off[c];
        int d = cnt[c];
        float a0 = 0.f, a1 = 0.f, ae = 0.f;
        for (int j = 0; j < d; j++) {              // wave-uniform loop
            unsigned s = (unsigned)srcE[beg + j];
            if (s >= N_NODES) continue;            // poison guard (diagnosable)
            float sv = dinv[s];
            float2 xv = ((const float2*)X)[s * 64 + l];
            a0 += sv * xv.x;
            a1 += sv * xv.y;
            if (mode == 0) {
                unsigned e = (unsigned)eidE[beg + j];
                if (e < N_EDGES) ae += sv * EAraw[e * 64 + l];
            }
        }
        float dv = dinv[c], dv2 = dv * dv;
        float2 xc = ((const float2*)X)[c * 64 + l];
        act[w][r][2 * l]     = dv * a0 + dv2 * xc.x;
        act[w][r][2 * l + 1] = dv * a1 + dv2 * xc.y;
        if (mode == 0) {
            act[w][r][128 + l] = dv * ae;
            EaOut[c * 64 + l] = ae;                // unscaled; layer 2 re-applies dv
        } else {
            act[w][r][128 + l] = dv * EaIn[c * 64 + l];
        }
    }
    __syncthreads();

    float acc[4][2] = {};
    for (int k = 0; k < 128; k++) {
        float2 wv = ((const float2*)Wn)[k * 64 + l];
        #pragma unroll
        for (int r = 0; r < 4; r++) {
            float a = act[w][r][k];
            acc[r][0] += a * wv.x;
            acc[r][1] += a * wv.y;
        }
    }
    for (int k = 0; k < 64; k++) {
        float2 wv = ((const float2*)We)[k * 64 + l];
        #pragma unroll
        for (int r = 0; r < 4; r++) {
            float a = act[w][r][128 + k];
            acc[r][0] += a * wv.x;
            acc[r][1] += a * wv.y;
        }
    }

    float2 bb = ((const float2*)bias)[l];
    for (int r = 0; r < 4; r++) {
        float v0 = acc[r][0] + bb.x;
        float v1 = acc[r][1] + bb.y;
        v0 = 0.5f * v0 * (1.0f + erff(v0 * 0.70710678f)); // exact gelu
        v1 = 0.5f * v1 * (1.0f + erff(v1 * 0.70710678f));
        float2 o; o.x = v0; o.y = v1;
        ((float2*)out)[(row0 + r) * 64 + l] = o;
    }
}

// ------------------------------------ final: h2 @ W_out + b_out + x, LayerNorm
// h2 lives in d_out; in-place safe: each block only touches its own 16 rows.
__global__ __launch_bounds__(256) void k_final(
    const float* __restrict__ h2, const float* __restrict__ x,
    const float* __restrict__ Wo, const float* __restrict__ bo,
    const float* __restrict__ g, const float* __restrict__ lb,
    float* __restrict__ out)
{
    __shared__ float lds[4][4][128];
    int w = threadIdx.x >> 6, l = threadIdx.x & 63;
    int row0 = blockIdx.x * 16 + w * 4;

    for (int r = 0; r < 4; r++) {
        int c = row0 + r;
        float2 hv = ((const float2*)h2)[c * 64 + l];
        lds[w][r][2 * l]     = hv.x;
        lds[w][r][2 * l + 1] = hv.y;
    }
    __syncthreads();

    float acc[4][2] = {};
    for (int k = 0; k < 128; k++) {
        float2 wv = ((const float2*)Wo)[k * 64 + l];
        #pragma unroll
        for (int r = 0; r < 4; r++) {
            float a = lds[w][r][k];
            acc[r][0] += a * wv.x;
            acc[r][1] += a * wv.y;
        }
    }

    float2 bov = ((const float2*)bo)[l];
    float2 gv  = ((const float2*)g)[l];
    float2 lbv = ((const float2*)lb)[l];

    for (int r = 0; r < 4; r++) {
        int c = row0 + r;
        float2 xv = ((const float2*)x)[c * 64 + l];
        float v0 = acc[r][0] + bov.x + xv.x;
        float v1 = acc[r][1] + bov.y + xv.y;
        float s = v0 + v1;
        #pragma unroll
        for (int o = 32; o; o >>= 1) s += __shfl_xor(s, o, 64);
        float mu = s * (1.0f / 128.0f);
        float d0 = v0 - mu, d1 = v1 - mu;
        float sq = d0 * d0 + d1 * d1;
        #pragma unroll
        for (int o = 32; o; o >>= 1) sq += __shfl_xor(sq, o, 64);
        float rs = rsqrtf(sq * (1.0f / 128.0f) + 1e-5f);
        float2 ov;
        ov.x = d0 * rs * gv.x + lbv.x;
        ov.y = d1 * rs * gv.y + lbv.y;
        ((float2*)out)[c * 64 + l] = ov;
    }
}

extern "C" void kernel_launch(void* const* d_in, const int* in_sizes, int n_in,
                              void* d_out, int out_size, void* d_ws, size_t ws_size,
                              hipStream_t stream)
{
    const float* x   = (const float*)d_in[0];
    const int*   ei  = (const int*)d_in[1];
    const float* ea  = (const float*)d_in[2];
    // d_in[3..6] (W_qkv, b_qkv, W_ek, b_ek) are dead code in the reference.
    const float* Wn1 = (const float*)d_in[7];
    const float* We1 = (const float*)d_in[8];
    const float* b1  = (const float*)d_in[9];
    const float* Wn2 = (const float*)d_in[10];
    const float* We2 = (const float*)d_in[11];
    const float* b2  = (const float*)d_in[12];
    const float* Wo  = (const float*)d_in[13];
    const float* bo  = (const float*)d_in[14];
    const float* lng = (const float*)d_in[15];
    const float* lnb = (const float*)d_in[16];
    const int* row = ei;
    const int* col = ei + N_EDGES;

    char* ws = (char*)d_ws;
    size_t off_b = 0;
    auto alloc = [&](size_t bytes) {
        void* p = ws + off_b;
        off_b += (bytes + 255) & ~(size_t)255;
        return p;
    };
    int*   cnt   = (int*)  alloc((size_t)N_NODES * 4);
    int*   off   = (int*)  alloc((size_t)N_NODES * 4);
    int*   pos   = (int*)  alloc((size_t)N_NODES * 4);
    int*   bsum  = (int*)  alloc((size_t)NBLK * 4);
    int*   bexcl = (int*)  alloc((size_t)NBLK * 4);
    float* dinv  = (float*)alloc((size_t)N_NODES * 4);
    int*   srcE  = (int*)  alloc((size_t)N_EDGES * 4);
    int*   eidE  = (int*)  alloc((size_t)N_EDGES * 4);
    float* Ea    = (float*)alloc((size_t)N_NODES * 64 * 4);
    float* h1    = (float*)alloc((size_t)N_NODES * 128 * 4);
    if (off_b > ws_size) return;  // finite-wrong signature (absmax ~5.1), not NaN

    float* h2 = (float*)d_out;    // staged in d_out; k_final runs in place

    hipMemsetAsync(cnt, 0, (size_t)N_NODES * 4, stream);

    k_count     <<<(N_EDGES + 255) / 256, 256, 0, stream>>>(col, cnt);
    k_blocksum  <<<NBLK, 256, 0, stream>>>(cnt, bsum);
    k_scanblocks<<<1, 64, 0, stream>>>(bsum, bexcl);
    k_offsets   <<<NBLK, 256, 0, stream>>>(cnt, bexcl, off, pos);
    k_dinv      <<<NBLK, 256, 0, stream>>>(cnt, dinv);
    k_build     <<<(N_EDGES + 255) / 256, 256, 0, stream>>>(row, col, pos, srcE, eidE);

    k_layer<<<N_NODES / 16, 256, 0, stream>>>(x, ea, nullptr, Ea,
                                              off, cnt, srcE, eidE, dinv,
                                              Wn1, We1, b1, h1, 0);
    k_layer<<<N_NODES / 16, 256, 0, stream>>>(h1, nullptr, Ea, nullptr,
                                              off, cnt, srcE, eidE, dinv,
                                              Wn2, We2, b2, h2, 1);
    k_final<<<N_NODES / 16, 256, 0, stream>>>(h2, x, Wo, bo, lng, lnb, (float*)d_out);
}

// Round 4
// 1128.510 us; speedup vs baseline: 2.1514x; 2.1514x over previous
//
#include <hip/hip_runtime.h>
#include <math.h>

#define N_NODES 100000
#define N_EDGES 800000
#define NBLK 391  // ceil(N_NODES/256)

// ----------------------------------------------------------- CSR construction
__global__ void k_count(const int* __restrict__ col, int* __restrict__ cnt) {
    int e = blockIdx.x * 256 + threadIdx.x;
    if (e < N_EDGES) {
        unsigned c = (unsigned)col[e];
        if (c < N_NODES) atomicAdd(&cnt[c], 1);
    }
}

__global__ void k_blocksum(const int* __restrict__ cnt, int* __restrict__ bsum) {
    __shared__ int sc[256];
    int t = threadIdx.x, i = blockIdx.x * 256 + t;
    sc[t] = (i < N_NODES) ? cnt[i] : 0;
    __syncthreads();
    for (int o = 128; o; o >>= 1) {
        if (t < o) sc[t] += sc[t + o];
        __syncthreads();
    }
    if (t == 0) bsum[blockIdx.x] = sc[0];
}

__global__ void k_scanblocks(const int* __restrict__ bsum, int* __restrict__ bexcl) {
    if (threadIdx.x == 0) {
        int run = 0;
        for (int b = 0; b < NBLK; b++) { bexcl[b] = run; run += bsum[b]; }
    }
}

__global__ void k_offsets(const int* __restrict__ cnt, const int* __restrict__ bexcl,
                          int* __restrict__ off, int* __restrict__ pos) {
    __shared__ int sc[256];
    int t = threadIdx.x, i = blockIdx.x * 256 + t;
    int v = (i < N_NODES) ? cnt[i] : 0;
    sc[t] = v;
    __syncthreads();
    for (int o = 1; o < 256; o <<= 1) {
        int tv = (t >= o) ? sc[t - o] : 0;
        __syncthreads();
        sc[t] += tv;
        __syncthreads();
    }
    if (i < N_NODES) {
        int s = bexcl[blockIdx.x] + (sc[t] - v);
        off[i] = s;
        pos[i] = s;
    }
}

__global__ void k_dinv(const int* __restrict__ cnt, float* __restrict__ dinv) {
    int i = blockIdx.x * 256 + threadIdx.x;
    if (i < N_NODES) dinv[i] = rsqrtf((float)(cnt[i] + 1)); // +1 self-loop
}

// builds CSR; also precomputes dinvE[slot] = dinv[src] to kill one gather indirection
__global__ void k_build(const int* __restrict__ row, const int* __restrict__ col,
                        int* __restrict__ pos, const float* __restrict__ dinv,
                        int* __restrict__ srcE, int* __restrict__ eidE,
                        float* __restrict__ dinvE) {
    int e = blockIdx.x * 256 + threadIdx.x;
    if (e < N_EDGES) {
        unsigned r = (unsigned)row[e], c = (unsigned)col[e];
        if (r < N_NODES && c < N_NODES) {
            int slot = atomicAdd(&pos[c], 1);
            srcE[slot] = (int)r;
            eidE[slot] = e;
            if (dinvE) dinvE[slot] = dinv[r];
        }
    }
}

// -------------------------------------------------- latency-optimized gather
// One wave per destination node. 4-wide unrolled edge loop: 4 independent
// 512B X-row loads (+4 256B ea-row loads in mode 0) in flight per wave.
// Writes UNNORMALIZED aggregates; k_gemm applies dinv scaling.
__global__ __launch_bounds__(256) void k_gather(
    const float* __restrict__ X, const float* __restrict__ EAraw,
    const int* __restrict__ off, const int* __restrict__ cnt,
    const int* __restrict__ srcE, const int* __restrict__ eidE,
    const float* __restrict__ dinvE,
    float* __restrict__ A, float* __restrict__ Ea, int mode)
{
    int w = threadIdx.x >> 6, l = threadIdx.x & 63;
    int c = blockIdx.x * 4 + w;
    if (c >= N_NODES) return;
    int beg = off[c], d = cnt[c];
    const float2* X2 = (const float2*)X;
    float a0 = 0.f, a1 = 0.f, ae = 0.f;

    int j = 0;
    for (; j + 4 <= d; j += 4) {
        int s0 = srcE[beg + j],     s1 = srcE[beg + j + 1];
        int s2 = srcE[beg + j + 2], s3 = srcE[beg + j + 3];
        float v0 = dinvE[beg + j],     v1 = dinvE[beg + j + 1];
        float v2 = dinvE[beg + j + 2], v3 = dinvE[beg + j + 3];
        float2 x0 = X2[(size_t)s0 * 64 + l];
        float2 x1 = X2[(size_t)s1 * 64 + l];
        float2 x2 = X2[(size_t)s2 * 64 + l];
        float2 x3 = X2[(size_t)s3 * 64 + l];
        a0 += v0 * x0.x + v1 * x1.x + v2 * x2.x + v3 * x3.x;
        a1 += v0 * x0.y + v1 * x1.y + v2 * x2.y + v3 * x3.y;
        if (mode == 0) {
            int e0 = eidE[beg + j],     e1 = eidE[beg + j + 1];
            int e2 = eidE[beg + j + 2], e3 = eidE[beg + j + 3];
            float q0 = EAraw[(size_t)e0 * 64 + l];
            float q1 = EAraw[(size_t)e1 * 64 + l];
            float q2 = EAraw[(size_t)e2 * 64 + l];
            float q3 = EAraw[(size_t)e3 * 64 + l];
            ae += v0 * q0 + v1 * q1 + v2 * q2 + v3 * q3;
        }
    }
    for (; j < d; j++) {
        int s = srcE[beg + j];
        float v = dinvE[beg + j];
        float2 xv = X2[(size_t)s * 64 + l];
        a0 += v * xv.x;
        a1 += v * xv.y;
        if (mode == 0) ae += v * EAraw[(size_t)eidE[beg + j] * 64 + l];
    }

    ((float2*)A)[(size_t)c * 64 + l] = make_float2(a0, a1);
    if (mode == 0) Ea[(size_t)c * 64 + l] = ae;
}

// -------------------------------------------------- compute-optimized GEMM
// out[c] = gelu( [dinv*A[c] + dinv^2*X[c] | dinv*Ea[c]] @ [Wn;We] + bias )
__global__ __launch_bounds__(256) void k_gemm(
    const float* __restrict__ A, const float* __restrict__ X,
    const float* __restrict__ Ea, const float* __restrict__ dinv,
    const float* __restrict__ Wn, const float* __restrict__ We,
    const float* __restrict__ bias, float* __restrict__ out)
{
    __shared__ float act[4][4][192];
    int w = threadIdx.x >> 6, l = threadIdx.x & 63;
    int row0 = blockIdx.x * 16 + w * 4;

    for (int r = 0; r < 4; r++) {
        int c = row0 + r;
        float dv = dinv[c], dv2 = dv * dv;
        float2 av = ((const float2*)A)[(size_t)c * 64 + l];
        float2 xv = ((const float2*)X)[(size_t)c * 64 + l];
        act[w][r][2 * l]     = dv * av.x + dv2 * xv.x;
        act[w][r][2 * l + 1] = dv * av.y + dv2 * xv.y;
        act[w][r][128 + l]   = dv * Ea[(size_t)c * 64 + l];
    }
    __syncthreads();

    float acc[4][2] = {};
    const float2* Wn2 = (const float2*)Wn;
    for (int k = 0; k < 128; k += 4) {
        float2 w0 = Wn2[(k + 0) * 64 + l];
        float2 w1 = Wn2[(k + 1) * 64 + l];
        float2 w2 = Wn2[(k + 2) * 64 + l];
        float2 w3 = Wn2[(k + 3) * 64 + l];
        #pragma unroll
        for (int r = 0; r < 4; r++) {
            float4 a = *(const float4*)&act[w][r][k];
            acc[r][0] += a.x * w0.x + a.y * w1.x + a.z * w2.x + a.w * w3.x;
            acc[r][1] += a.x * w0.y + a.y * w1.y + a.z * w2.y + a.w * w3.y;
        }
    }
    const float2* We2 = (const float2*)We;
    for (int k = 0; k < 64; k += 4) {
        float2 w0 = We2[(k + 0) * 64 + l];
        float2 w1 = We2[(k + 1) * 64 + l];
        float2 w2 = We2[(k + 2) * 64 + l];
        float2 w3 = We2[(k + 3) * 64 + l];
        #pragma unroll
        for (int r = 0; r < 4; r++) {
            float4 a = *(const float4*)&act[w][r][128 + k];
            acc[r][0] += a.x * w0.x + a.y * w1.x + a.z * w2.x + a.w * w3.x;
            acc[r][1] += a.x * w0.y + a.y * w1.y + a.z * w2.y + a.w * w3.y;
        }
    }

    float2 bb = ((const float2*)bias)[l];
    for (int r = 0; r < 4; r++) {
        float v0 = acc[r][0] + bb.x;
        float v1 = acc[r][1] + bb.y;
        v0 = 0.5f * v0 * (1.0f + erff(v0 * 0.70710678f)); // exact gelu
        v1 = 0.5f * v1 * (1.0f + erff(v1 * 0.70710678f));
        ((float2*)out)[(size_t)(row0 + r) * 64 + l] = make_float2(v0, v1);
    }
}

// --------------------- fused fallback (round-3 proven path, small workspace)
__global__ __launch_bounds__(256) void k_layer(
    const float* __restrict__ X, const float* __restrict__ EAraw,
    const float* __restrict__ EaIn, float* __restrict__ EaOut,
    const int* __restrict__ off, const int* __restrict__ cnt,
    const int* __restrict__ srcE, const int* __restrict__ eidE,
    const float* __restrict__ dinv,
    const float* __restrict__ Wn, const float* __restrict__ We,
    const float* __restrict__ bias, float* __restrict__ out, int mode)
{
    __shared__ float act[4][4][192];
    int w = threadIdx.x >> 6, l = threadIdx.x & 63;
    int row0 = blockIdx.x * 16 + w * 4;

    for (int r = 0; r < 4; r++) {
        int c = row0 + r;
        int beg = off[c];
        int d = cnt[c];
        float a0 = 0.f, a1 = 0.f, ae = 0.f;
        for (int j = 0; j < d; j++) {
            unsigned s = (unsigned)srcE[beg + j];
            if (s >= N_NODES) continue;
            float sv = dinv[s];
            float2 xv = ((const float2*)X)[s * 64 + l];
            a0 += sv * xv.x;
            a1 += sv * xv.y;
            if (mode == 0) {
                unsigned e = (unsigned)eidE[beg + j];
                if (e < N_EDGES) ae += sv * EAraw[e * 64 + l];
            }
        }
        float dv = dinv[c], dv2 = dv * dv;
        float2 xc = ((const float2*)X)[c * 64 + l];
        act[w][r][2 * l]     = dv * a0 + dv2 * xc.x;
        act[w][r][2 * l + 1] = dv * a1 + dv2 * xc.y;
        if (mode == 0) {
            act[w][r][128 + l] = dv * ae;
            EaOut[c * 64 + l] = ae;
        } else {
            act[w][r][128 + l] = dv * EaIn[c * 64 + l];
        }
    }
    __syncthreads();

    float acc[4][2] = {};
    for (int k = 0; k < 128; k++) {
        float2 wv = ((const float2*)Wn)[k * 64 + l];
        #pragma unroll
        for (int r = 0; r < 4; r++) {
            float a = act[w][r][k];
            acc[r][0] += a * wv.x;
            acc[r][1] += a * wv.y;
        }
    }
    for (int k = 0; k < 64; k++) {
        float2 wv = ((const float2*)We)[k * 64 + l];
        #pragma unroll
        for (int r = 0; r < 4; r++) {
            float a = act[w][r][128 + k];
            acc[r][0] += a * wv.x;
            acc[r][1] += a * wv.y;
        }
    }

    float2 bb = ((const float2*)bias)[l];
    for (int r = 0; r < 4; r++) {
        float v0 = acc[r][0] + bb.x;
        float v1 = acc[r][1] + bb.y;
        v0 = 0.5f * v0 * (1.0f + erff(v0 * 0.70710678f));
        v1 = 0.5f * v1 * (1.0f + erff(v1 * 0.70710678f));
        ((float2*)out)[(row0 + r) * 64 + l] = make_float2(v0, v1);
    }
}

// ------------------------------------ final: h2 @ W_out + b_out + x, LayerNorm
__global__ __launch_bounds__(256) void k_final(
    const float* __restrict__ h2, const float* __restrict__ x,
    const float* __restrict__ Wo, const float* __restrict__ bo,
    const float* __restrict__ g, const float* __restrict__ lb,
    float* __restrict__ out)
{
    __shared__ float lds[4][4][128];
    int w = threadIdx.x >> 6, l = threadIdx.x & 63;
    int row0 = blockIdx.x * 16 + w * 4;

    for (int r = 0; r < 4; r++) {
        int c = row0 + r;
        float2 hv = ((const float2*)h2)[(size_t)c * 64 + l];
        lds[w][r][2 * l]     = hv.x;
        lds[w][r][2 * l + 1] = hv.y;
    }
    __syncthreads();

    float acc[4][2] = {};
    const float2* Wo2 = (const float2*)Wo;
    for (int k = 0; k < 128; k += 4) {
        float2 w0 = Wo2[(k + 0) * 64 + l];
        float2 w1 = Wo2[(k + 1) * 64 + l];
        float2 w2 = Wo2[(k + 2) * 64 + l];
        float2 w3 = Wo2[(k + 3) * 64 + l];
        #pragma unroll
        for (int r = 0; r < 4; r++) {
            float4 a = *(const float4*)&lds[w][r][k];
            acc[r][0] += a.x * w0.x + a.y * w1.x + a.z * w2.x + a.w * w3.x;
            acc[r][1] += a.x * w0.y + a.y * w1.y + a.z * w2.y + a.w * w3.y;
        }
    }

    float2 bov = ((const float2*)bo)[l];
    float2 gv  = ((const float2*)g)[l];
    float2 lbv = ((const float2*)lb)[l];

    for (int r = 0; r < 4; r++) {
        int c = row0 + r;
        float2 xv = ((const float2*)x)[(size_t)c * 64 + l];
        float v0 = acc[r][0] + bov.x + xv.x;
        float v1 = acc[r][1] + bov.y + xv.y;
        float s = v0 + v1;
        #pragma unroll
        for (int o = 32; o; o >>= 1) s += __shfl_xor(s, o, 64);
        float mu = s * (1.0f / 128.0f);
        float d0 = v0 - mu, d1 = v1 - mu;
        float sq = d0 * d0 + d1 * d1;
        #pragma unroll
        for (int o = 32; o; o >>= 1) sq += __shfl_xor(sq, o, 64);
        float rs = rsqrtf(sq * (1.0f / 128.0f) + 1e-5f);
        float2 ov;
        ov.x = d0 * rs * gv.x + lbv.x;
        ov.y = d1 * rs * gv.y + lbv.y;
        ((float2*)out)[(size_t)c * 64 + l] = ov;
    }
}

extern "C" void kernel_launch(void* const* d_in, const int* in_sizes, int n_in,
                              void* d_out, int out_size, void* d_ws, size_t ws_size,
                              hipStream_t stream)
{
    const float* x   = (const float*)d_in[0];
    const int*   ei  = (const int*)d_in[1];
    const float* ea  = (const float*)d_in[2];
    // d_in[3..6] (W_qkv, b_qkv, W_ek, b_ek) are dead code in the reference.
    const float* Wn1 = (const float*)d_in[7];
    const float* We1 = (const float*)d_in[8];
    const float* b1  = (const float*)d_in[9];
    const float* Wn2 = (const float*)d_in[10];
    const float* We2 = (const float*)d_in[11];
    const float* b2  = (const float*)d_in[12];
    const float* Wo  = (const float*)d_in[13];
    const float* bo  = (const float*)d_in[14];
    const float* lng = (const float*)d_in[15];
    const float* lnb = (const float*)d_in[16];
    const int* row = ei;
    const int* col = ei + N_EDGES;

    char* ws = (char*)d_ws;
    size_t off_b = 0;
    auto alloc = [&](size_t bytes) {
        void* p = ws + off_b;
        off_b += (bytes + 255) & ~(size_t)255;
        return p;
    };
    // ---- common CSR workspace (~8 MB)
    int*   cnt   = (int*)  alloc((size_t)N_NODES * 4);
    int*   off   = (int*)  alloc((size_t)N_NODES * 4);
    int*   pos   = (int*)  alloc((size_t)N_NODES * 4);
    int*   bsum  = (int*)  alloc((size_t)NBLK * 4);
    int*   bexcl = (int*)  alloc((size_t)NBLK * 4);
    float* dinv  = (float*)alloc((size_t)N_NODES * 4);
    int*   srcE  = (int*)  alloc((size_t)N_EDGES * 4);
    int*   eidE  = (int*)  alloc((size_t)N_EDGES * 4);
    float* Ea    = (float*)alloc((size_t)N_NODES * 64 * 4);
    float* h1    = (float*)alloc((size_t)N_NODES * 128 * 4);
    size_t fused_end = off_b;
    float* dinvE = (float*)alloc((size_t)N_EDGES * 4);
    float* A     = (float*)alloc((size_t)N_NODES * 128 * 4);
    size_t split_end = off_b;

    bool use_split = (split_end <= ws_size);
    if (!use_split && fused_end > ws_size) return; // finite-wrong signature, diagnosable

    float* h2 = (float*)d_out;    // staged in d_out; k_final runs in place

    hipMemsetAsync(cnt, 0, (size_t)N_NODES * 4, stream);

    k_count     <<<(N_EDGES + 255) / 256, 256, 0, stream>>>(col, cnt);
    k_blocksum  <<<NBLK, 256, 0, stream>>>(cnt, bsum);
    k_scanblocks<<<1, 64, 0, stream>>>(bsum, bexcl);
    k_offsets   <<<NBLK, 256, 0, stream>>>(cnt, bexcl, off, pos);
    k_dinv      <<<NBLK, 256, 0, stream>>>(cnt, dinv);
    k_build     <<<(N_EDGES + 255) / 256, 256, 0, stream>>>(
        row, col, pos, dinv, srcE, eidE, use_split ? dinvE : nullptr);

    if (use_split) {
        k_gather<<<N_NODES / 4, 256, 0, stream>>>(x, ea, off, cnt, srcE, eidE, dinvE,
                                                  A, Ea, 0);
        k_gemm  <<<N_NODES / 16, 256, 0, stream>>>(A, x, Ea, dinv, Wn1, We1, b1, h1);
        k_gather<<<N_NODES / 4, 256, 0, stream>>>(h1, nullptr, off, cnt, srcE, eidE, dinvE,
                                                  A, nullptr, 1);
        k_gemm  <<<N_NODES / 16, 256, 0, stream>>>(A, h1, Ea, dinv, Wn2, We2, b2, h2);
    } else {
        k_layer<<<N_NODES / 16, 256, 0, stream>>>(x, ea, nullptr, Ea,
                                                  off, cnt, srcE, eidE, dinv,
                                                  Wn1, We1, b1, h1, 0);
        k_layer<<<N_NODES / 16, 256, 0, stream>>>(h1, nullptr, Ea, nullptr,
                                                  off, cnt, srcE, eidE, dinv,
                                                  Wn2, We2, b2, h2, 1);
    }
    k_final<<<N_NODES / 16, 256, 0, stream>>>(h2, x, Wo, bo, lng, lnb, (float*)d_out);
}